// Round 1
// baseline (1010.293 us; speedup 1.0000x reference)
//
#include <hip/hip_runtime.h>
#include <math.h>

#define BB 2
#define NN 2048
#define HID 896
#define HQ 14
#define HKV 2
#define DD 64
#define QKV_COLS 1152

// ---------------------------------------------------------------------------
// Generic tiled FP32 GEMM: out[m][n] = sum_k A[m][k]*W[k][n] (+bias[n])
// A: [4096 x 896] (lda = 896 fixed). Block: 256 thr, 64x64 tile, BK=32,
// 4x4 micro-tile per thread. grid = (ncols/64, 4096/64).
// ---------------------------------------------------------------------------
#define GSTEP(AC, BV) \
  acc[0][0] += a0.AC*BV.x; acc[0][1] += a0.AC*BV.y; acc[0][2] += a0.AC*BV.z; acc[0][3] += a0.AC*BV.w; \
  acc[1][0] += a1.AC*BV.x; acc[1][1] += a1.AC*BV.y; acc[1][2] += a1.AC*BV.z; acc[1][3] += a1.AC*BV.w; \
  acc[2][0] += a2.AC*BV.x; acc[2][1] += a2.AC*BV.y; acc[2][2] += a2.AC*BV.z; acc[2][3] += a2.AC*BV.w; \
  acc[3][0] += a3.AC*BV.x; acc[3][1] += a3.AC*BV.y; acc[3][2] += a3.AC*BV.z; acc[3][3] += a3.AC*BV.w;

__global__ __launch_bounds__(256)
void gemm_kernel(const float* __restrict__ A, const float* __restrict__ W,
                 const float* __restrict__ bias, float* __restrict__ out,
                 int ldw, int ldout)
{
  const int n0 = blockIdx.x * 64;
  const int m0 = blockIdx.y * 64;
  __shared__ float As[64 * 36];   // As[m][kk], stride 36
  __shared__ float Bs[32 * 68];   // Bs[kk][n], stride 68
  const int t  = threadIdx.x;
  const int tn = t & 15, tm = t >> 4;
  float acc[4][4];
#pragma unroll
  for (int i = 0; i < 4; i++)
#pragma unroll
    for (int j = 0; j < 4; j++) acc[i][j] = 0.f;

  for (int k0 = 0; k0 < HID; k0 += 32) {
    // A tile 64x32: 512 float4, 2 per thread, coalesced along k
#pragma unroll
    for (int i = 0; i < 2; i++) {
      int idx4 = t + i * 256;
      int r = idx4 >> 3, c4 = idx4 & 7;
      float4 v = *(const float4*)(A + (size_t)(m0 + r) * HID + k0 + c4 * 4);
      *(float4*)(&As[r * 36 + c4 * 4]) = v;
    }
    // B tile 32x64: 512 float4, 2 per thread, coalesced along n
#pragma unroll
    for (int i = 0; i < 2; i++) {
      int idx4 = t + i * 256;
      int kk = idx4 >> 4, c4 = idx4 & 15;
      float4 v = *(const float4*)(W + (size_t)(k0 + kk) * ldw + n0 + c4 * 4);
      *(float4*)(&Bs[kk * 68 + c4 * 4]) = v;
    }
    __syncthreads();
#pragma unroll
    for (int kk = 0; kk < 32; kk += 4) {
      float4 a0 = *(const float4*)(&As[(tm * 4 + 0) * 36 + kk]);
      float4 a1 = *(const float4*)(&As[(tm * 4 + 1) * 36 + kk]);
      float4 a2 = *(const float4*)(&As[(tm * 4 + 2) * 36 + kk]);
      float4 a3 = *(const float4*)(&As[(tm * 4 + 3) * 36 + kk]);
      float4 b0 = *(const float4*)(&Bs[(kk + 0) * 68 + tn * 4]);
      float4 b1 = *(const float4*)(&Bs[(kk + 1) * 68 + tn * 4]);
      float4 b2 = *(const float4*)(&Bs[(kk + 2) * 68 + tn * 4]);
      float4 b3 = *(const float4*)(&Bs[(kk + 3) * 68 + tn * 4]);
      GSTEP(x, b0)
      GSTEP(y, b1)
      GSTEP(z, b2)
      GSTEP(w, b3)
    }
    __syncthreads();
  }
  const int row = m0 + tm * 4;
  const int col = n0 + tn * 4;
  float b0 = 0.f, b1 = 0.f, b2 = 0.f, b3 = 0.f;
  if (bias) { b0 = bias[col]; b1 = bias[col + 1]; b2 = bias[col + 2]; b3 = bias[col + 3]; }
#pragma unroll
  for (int i = 0; i < 4; i++) {
    float4 o = make_float4(acc[i][0] + b0, acc[i][1] + b1, acc[i][2] + b2, acc[i][3] + b3);
    *(float4*)(out + (size_t)(row + i) * ldout + col) = o;
  }
}

// ---------------------------------------------------------------------------
// RoPE + scatter: qkv [4096 x 1152] -> Q [B,HQ,N,D], K [B,HKV,N,D], V [B,HKV,N,D]
// grid = 4096 blocks (one per (b,n) row), 256 threads.
// ---------------------------------------------------------------------------
__global__ __launch_bounds__(256)
void rope_kernel(const float* __restrict__ qkv, const int* __restrict__ pos_ids,
                 float* __restrict__ Qo, float* __restrict__ Ko, float* __restrict__ Vo)
{
  const int m = blockIdx.x;            // 0..4095
  const int b = m >> 11, n = m & (NN - 1);
  const int t = threadIdx.x;
  __shared__ float cs[32], sn[32];
  if (t < 32) {
    // inv_freq = 1e6^(-t/32) = 2^(-t/32 * log2(1e6))
    float inv = exp2f(-(float)t * (19.9315685693241741f / 32.0f));
    float f = (float)pos_ids[m] * inv;
    float sv, cv;
    sincosf(f, &sv, &cv);
    cs[t] = cv; sn[t] = sv;
  }
  __syncthreads();
  const float* row = qkv + (size_t)m * QKV_COLS;
#pragma unroll
  for (int it = 0; it < 2; it++) {
    int idx = t + it * 256;            // 0..511 : 16 heads x 32 pairs
    int hh = idx >> 5, d = idx & 31;
    const float* src; float* dst;
    if (hh < HQ) {
      src = row + hh * DD;
      dst = Qo + ((size_t)(b * HQ + hh) * NN + n) * DD;
    } else {
      int kh = hh - HQ;
      src = row + HID + kh * DD;
      dst = Ko + ((size_t)(b * HKV + kh) * NN + n) * DD;
    }
    float x1 = src[d], x2 = src[d + 32];
    dst[d]      = x1 * cs[d] - x2 * sn[d];
    dst[d + 32] = x2 * cs[d] + x1 * sn[d];
  }
  if (t < 128) {
    int hh = t >> 6, d = t & 63;
    Vo[((size_t)(b * HKV + hh) * NN + n) * DD + d] = row[HID + HKV * DD + hh * DD + d];
  }
}

// ---------------------------------------------------------------------------
// Causal GQA flash attention, fp32. One block per (qtile, h, b). 256 threads.
// Thread t owns Q-row qr=t>>2, 16 S-columns starting at (t&3)*16.
// KS buffer holds K^T during S-compute, then P (=exp(S-m)) for PV.
// ---------------------------------------------------------------------------
#define ST 68
__global__ __launch_bounds__(256)
void attn_kernel(const float* __restrict__ Q, const float* __restrict__ K,
                 const float* __restrict__ V, float* __restrict__ O)
{
  const int qt = (int)gridDim.x - 1 - (int)blockIdx.x;  // long blocks launch first
  const int h = blockIdx.y, b = blockIdx.z;
  const int kvh = h / (HQ / HKV);
  const int q0 = qt * 64;
  __shared__ float Qs[64 * ST];
  __shared__ float KS[64 * ST];   // K^T, then P
  __shared__ float Vs[64 * ST];
  __shared__ float m_s[64], l_s[64];
  const int t = threadIdx.x;
  const int qr = t >> 2, cg = t & 3;
  const int c0 = cg * 16;
  float acc[16];
#pragma unroll
  for (int i = 0; i < 16; i++) acc[i] = 0.f;
  if (t < 64) { m_s[t] = -1e30f; l_s[t] = 0.f; }

  const float* Qb = Q + ((size_t)(b * HQ + h) * NN + q0) * DD;
#pragma unroll
  for (int i = 0; i < 16; i++) {        // 4096 scalars, coalesced
    int idx = t + i * 256;
    int r = idx >> 6, d = idx & 63;
    Qs[r * ST + d] = Qb[r * DD + d];
  }
  const float* Kb = K + (size_t)(b * HKV + kvh) * NN * DD;
  const float* Vb = V + (size_t)(b * HKV + kvh) * NN * DD;

  for (int j = 0; j <= qt; j++) {
    __syncthreads();                    // prev PV done; also covers Q-load for j=0 via next sync
    // stage K (transposed) and V tiles
#pragma unroll
    for (int i = 0; i < 4; i++) {
      int idx4 = t + i * 256;
      int r = idx4 >> 4, c4 = idx4 & 15;
      float4 kv = *(const float4*)(Kb + (size_t)(j * 64 + r) * DD + c4 * 4);
      KS[(c4 * 4 + 0) * ST + r] = kv.x;
      KS[(c4 * 4 + 1) * ST + r] = kv.y;
      KS[(c4 * 4 + 2) * ST + r] = kv.z;
      KS[(c4 * 4 + 3) * ST + r] = kv.w;
      float4 vv = *(const float4*)(Vb + (size_t)(j * 64 + r) * DD + c4 * 4);
      *(float4*)(&Vs[r * ST + c4 * 4]) = vv;
    }
    __syncthreads();
    // S = Q K^T
    float s[16];
#pragma unroll
    for (int c = 0; c < 16; c++) s[c] = 0.f;
    for (int d = 0; d < 64; d++) {
      float qv = Qs[qr * ST + d];
      const float4* kr = (const float4*)(&KS[d * ST + c0]);
      float4 k0v = kr[0], k1v = kr[1], k2v = kr[2], k3v = kr[3];
      s[0]  += qv * k0v.x; s[1]  += qv * k0v.y; s[2]  += qv * k0v.z; s[3]  += qv * k0v.w;
      s[4]  += qv * k1v.x; s[5]  += qv * k1v.y; s[6]  += qv * k1v.z; s[7]  += qv * k1v.w;
      s[8]  += qv * k2v.x; s[9]  += qv * k2v.y; s[10] += qv * k2v.z; s[11] += qv * k2v.w;
      s[12] += qv * k3v.x; s[13] += qv * k3v.y; s[14] += qv * k3v.z; s[15] += qv * k3v.w;
    }
    const float scale = 0.125f;         // 1/sqrt(64)
    if (j == qt) {
      int qg = q0 + qr;
#pragma unroll
      for (int c = 0; c < 16; c++) {
        int kg = j * 64 + c0 + c;
        s[c] = (kg <= qg) ? s[c] * scale : -1e30f;
      }
    } else {
#pragma unroll
      for (int c = 0; c < 16; c++) s[c] *= scale;
    }
    // online softmax: state for row qr shared by 4 lanes of the same wave
    float mt = s[0];
#pragma unroll
    for (int c = 1; c < 16; c++) mt = fmaxf(mt, s[c]);
    mt = fmaxf(mt, __shfl_xor(mt, 1));
    mt = fmaxf(mt, __shfl_xor(mt, 2));
    float mold = m_s[qr];
    float mnew = fmaxf(mold, mt);
    float alpha = __expf(mold - mnew);
    float lsum = 0.f;
#pragma unroll
    for (int c = 0; c < 16; c++) { s[c] = __expf(s[c] - mnew); lsum += s[c]; }
    lsum += __shfl_xor(lsum, 1);
    lsum += __shfl_xor(lsum, 2);
    __syncthreads();                    // all K^T reads done -> reuse KS for P
    *(float4*)(&KS[qr * ST + c0 + 0])  = make_float4(s[0],  s[1],  s[2],  s[3]);
    *(float4*)(&KS[qr * ST + c0 + 4])  = make_float4(s[4],  s[5],  s[6],  s[7]);
    *(float4*)(&KS[qr * ST + c0 + 8])  = make_float4(s[8],  s[9],  s[10], s[11]);
    *(float4*)(&KS[qr * ST + c0 + 12]) = make_float4(s[12], s[13], s[14], s[15]);
    if (cg == 0) {
      l_s[qr] = l_s[qr] * alpha + lsum;
      m_s[qr] = mnew;
    }
    __syncthreads();
    // O += P V
#pragma unroll
    for (int c = 0; c < 16; c++) acc[c] *= alpha;
    for (int k = 0; k < 64; k++) {
      float pv = KS[qr * ST + k];
      const float4* vr = (const float4*)(&Vs[k * ST + c0]);
      float4 v0 = vr[0], v1 = vr[1], v2 = vr[2], v3 = vr[3];
      acc[0]  += pv * v0.x; acc[1]  += pv * v0.y; acc[2]  += pv * v0.z; acc[3]  += pv * v0.w;
      acc[4]  += pv * v1.x; acc[5]  += pv * v1.y; acc[6]  += pv * v1.z; acc[7]  += pv * v1.w;
      acc[8]  += pv * v2.x; acc[9]  += pv * v2.y; acc[10] += pv * v2.z; acc[11] += pv * v2.w;
      acc[12] += pv * v3.x; acc[13] += pv * v3.y; acc[14] += pv * v3.z; acc[15] += pv * v3.w;
    }
  }
  const float linv = 1.f / (l_s[qr] + 1e-8f);
  float* Op = O + (size_t)(b * NN + q0 + qr) * HID + h * DD + c0;
  *(float4*)(Op + 0)  = make_float4(acc[0]  * linv, acc[1]  * linv, acc[2]  * linv, acc[3]  * linv);
  *(float4*)(Op + 4)  = make_float4(acc[4]  * linv, acc[5]  * linv, acc[6]  * linv, acc[7]  * linv);
  *(float4*)(Op + 8)  = make_float4(acc[8]  * linv, acc[9]  * linv, acc[10] * linv, acc[11] * linv);
  *(float4*)(Op + 12) = make_float4(acc[12] * linv, acc[13] * linv, acc[14] * linv, acc[15] * linv);
}

// ---------------------------------------------------------------------------
extern "C" void kernel_launch(void* const* d_in, const int* in_sizes, int n_in,
                              void* d_out, int out_size, void* d_ws, size_t ws_size,
                              hipStream_t stream)
{
  const float* hid = (const float*)d_in[0];
  const int*   pos = (const int*)  d_in[1];
  const float* qw  = (const float*)d_in[2];
  const float* qb  = (const float*)d_in[3];
  const float* kw  = (const float*)d_in[4];
  const float* kb  = (const float*)d_in[5];
  const float* vw  = (const float*)d_in[6];
  const float* vb  = (const float*)d_in[7];
  const float* ow  = (const float*)d_in[8];
  float* outp = (float*)d_out;

  // workspace layout (floats): qkv [4096*1152] | Q [2*14*2048*64] | K | V
  // attention output O reuses the qkv buffer (dead after rope_kernel).
  float* qkv = (float*)d_ws;
  float* Qb  = qkv + (size_t)4096 * QKV_COLS;
  float* Kb  = Qb  + (size_t)BB * HQ  * NN * DD;
  float* Vb  = Kb  + (size_t)BB * HKV * NN * DD;
  float* Ob  = qkv;   // reuse

  gemm_kernel<<<dim3(14, 64), 256, 0, stream>>>(hid, qw, qb, qkv,        896, QKV_COLS);
  gemm_kernel<<<dim3(2, 64),  256, 0, stream>>>(hid, kw, kb, qkv + 896,  128, QKV_COLS);
  gemm_kernel<<<dim3(2, 64),  256, 0, stream>>>(hid, vw, vb, qkv + 1024, 128, QKV_COLS);
  rope_kernel<<<dim3(4096),   256, 0, stream>>>(qkv, pos, Qb, Kb, Vb);
  attn_kernel<<<dim3(NN / 64, HQ, BB), 256, 0, stream>>>(Qb, Kb, Vb, Ob);
  gemm_kernel<<<dim3(14, 64), 256, 0, stream>>>(Ob, ow, nullptr, outp, 896, 896);
}

// Round 2
// 469.586 us; speedup vs baseline: 2.1515x; 2.1515x over previous
//
#include <hip/hip_runtime.h>
#include <math.h>

#define BB 2
#define NN 2048
#define HID 896
#define HQ 14
#define HKV 2
#define DD 64
#define QKV_COLS 1152

typedef __bf16 bf16x8 __attribute__((ext_vector_type(8)));
typedef float f32x4 __attribute__((ext_vector_type(4)));

__device__ inline ushort f2bs(float f) {   // fp32 -> bf16 (RNE), finite inputs
  uint u = __builtin_bit_cast(uint, f);
  u += 0x7FFFu + ((u >> 16) & 1u);
  return (ushort)(u >> 16);
}

// ---------------------------------------------------------------------------
// Generic tiled FP32 GEMM: out[m][n] = sum_k A[m][k]*W[k][n] (+bias[n])
// ---------------------------------------------------------------------------
#define GSTEP(AC, BV) \
  acc[0][0] += a0.AC*BV.x; acc[0][1] += a0.AC*BV.y; acc[0][2] += a0.AC*BV.z; acc[0][3] += a0.AC*BV.w; \
  acc[1][0] += a1.AC*BV.x; acc[1][1] += a1.AC*BV.y; acc[1][2] += a1.AC*BV.z; acc[1][3] += a1.AC*BV.w; \
  acc[2][0] += a2.AC*BV.x; acc[2][1] += a2.AC*BV.y; acc[2][2] += a2.AC*BV.z; acc[2][3] += a2.AC*BV.w; \
  acc[3][0] += a3.AC*BV.x; acc[3][1] += a3.AC*BV.y; acc[3][2] += a3.AC*BV.z; acc[3][3] += a3.AC*BV.w;

__global__ __launch_bounds__(256)
void gemm_kernel(const float* __restrict__ A, const float* __restrict__ W,
                 const float* __restrict__ bias, float* __restrict__ out,
                 int ldw, int ldout)
{
  const int n0 = blockIdx.x * 64;
  const int m0 = blockIdx.y * 64;
  __shared__ float As[64 * 36];
  __shared__ float Bs[32 * 68];
  const int t  = threadIdx.x;
  const int tn = t & 15, tm = t >> 4;
  float acc[4][4];
#pragma unroll
  for (int i = 0; i < 4; i++)
#pragma unroll
    for (int j = 0; j < 4; j++) acc[i][j] = 0.f;

  for (int k0 = 0; k0 < HID; k0 += 32) {
#pragma unroll
    for (int i = 0; i < 2; i++) {
      int idx4 = t + i * 256;
      int r = idx4 >> 3, c4 = idx4 & 7;
      float4 v = *(const float4*)(A + (size_t)(m0 + r) * HID + k0 + c4 * 4);
      *(float4*)(&As[r * 36 + c4 * 4]) = v;
    }
#pragma unroll
    for (int i = 0; i < 2; i++) {
      int idx4 = t + i * 256;
      int kk = idx4 >> 4, c4 = idx4 & 15;
      float4 v = *(const float4*)(W + (size_t)(k0 + kk) * ldw + n0 + c4 * 4);
      *(float4*)(&Bs[kk * 68 + c4 * 4]) = v;
    }
    __syncthreads();
#pragma unroll
    for (int kk = 0; kk < 32; kk += 4) {
      float4 a0 = *(const float4*)(&As[(tm * 4 + 0) * 36 + kk]);
      float4 a1 = *(const float4*)(&As[(tm * 4 + 1) * 36 + kk]);
      float4 a2 = *(const float4*)(&As[(tm * 4 + 2) * 36 + kk]);
      float4 a3 = *(const float4*)(&As[(tm * 4 + 3) * 36 + kk]);
      float4 b0 = *(const float4*)(&Bs[(kk + 0) * 68 + tn * 4]);
      float4 b1 = *(const float4*)(&Bs[(kk + 1) * 68 + tn * 4]);
      float4 b2 = *(const float4*)(&Bs[(kk + 2) * 68 + tn * 4]);
      float4 b3 = *(const float4*)(&Bs[(kk + 3) * 68 + tn * 4]);
      GSTEP(x, b0)
      GSTEP(y, b1)
      GSTEP(z, b2)
      GSTEP(w, b3)
    }
    __syncthreads();
  }
  const int row = m0 + tm * 4;
  const int col = n0 + tn * 4;
  float b0 = 0.f, b1 = 0.f, b2 = 0.f, b3 = 0.f;
  if (bias) { b0 = bias[col]; b1 = bias[col + 1]; b2 = bias[col + 2]; b3 = bias[col + 3]; }
#pragma unroll
  for (int i = 0; i < 4; i++) {
    float4 o = make_float4(acc[i][0] + b0, acc[i][1] + b1, acc[i][2] + b2, acc[i][3] + b3);
    *(float4*)(out + (size_t)(row + i) * ldout + col) = o;
  }
}

// ---------------------------------------------------------------------------
// RoPE + scatter -> bf16: Q [B,HQ,N,D], K [B,HKV,N,D], Vt [B,HKV,D,N] (transposed!)
// ---------------------------------------------------------------------------
__global__ __launch_bounds__(256)
void rope_kernel(const float* __restrict__ qkv, const int* __restrict__ pos_ids,
                 ushort* __restrict__ Qo, ushort* __restrict__ Ko, ushort* __restrict__ Vto)
{
  const int m = blockIdx.x;
  const int b = m >> 11, n = m & (NN - 1);
  const int t = threadIdx.x;
  __shared__ float cs[32], sn[32];
  if (t < 32) {
    float inv = exp2f(-(float)t * (19.9315685693241741f / 32.0f));
    float f = (float)pos_ids[m] * inv;
    float sv, cv;
    sincosf(f, &sv, &cv);
    cs[t] = cv; sn[t] = sv;
  }
  __syncthreads();
  const float* row = qkv + (size_t)m * QKV_COLS;
#pragma unroll
  for (int it = 0; it < 2; it++) {
    int idx = t + it * 256;
    int hh = idx >> 5, d = idx & 31;
    const float* src; ushort* dst;
    if (hh < HQ) {
      src = row + hh * DD;
      dst = Qo + ((size_t)(b * HQ + hh) * NN + n) * DD;
    } else {
      int kh = hh - HQ;
      src = row + HID + kh * DD;
      dst = Ko + ((size_t)(b * HKV + kh) * NN + n) * DD;
    }
    float x1 = src[d], x2 = src[d + 32];
    dst[d]      = f2bs(x1 * cs[d] - x2 * sn[d]);
    dst[d + 32] = f2bs(x2 * cs[d] + x1 * sn[d]);
  }
  if (t < 128) {
    int hh = t >> 6, d = t & 63;
    Vto[((size_t)(b * HKV + hh) * DD + d) * NN + n] = f2bs(row[HID + HKV * DD + hh * DD + d]);
  }
}

// ---------------------------------------------------------------------------
// bf16 MFMA flash attention. Block = 256 thr = 4 waves; wave w owns Q-rows
// q0+16w..+15 (A-frags in registers). KV tiles of 64 staged in LDS (K natural,
// V pre-transposed by rope_kernel). Online softmax per C-layout row held in a
// 16-lane quad (shuffle reductions, no LDS state). P -> wave-private LDS ->
// A-layout for PV (m120-verified transform). All LDS strides = 72 bf16.
// ---------------------------------------------------------------------------
#define LS 72
__global__ __launch_bounds__(256)
void attn_kernel(const ushort* __restrict__ Q, const ushort* __restrict__ K,
                 const ushort* __restrict__ Vt, float* __restrict__ O)
{
  const int qt = (int)gridDim.x - 1 - (int)blockIdx.x;  // long blocks first
  const int h = blockIdx.y, b = blockIdx.z;
  const int kvh = h / (HQ / HKV);
  const int q0 = qt * 64;

  __shared__ ushort Ks[64 * LS];
  __shared__ ushort Vs[64 * LS];     // V^T tile: [d][kv]
  __shared__ ushort Ps[4][16 * LS];  // wave-private P

  const int t = threadIdx.x;
  const int w = t >> 6, lane = t & 63;
  const int quad = lane >> 4, nn = lane & 15;
  ushort* PsW = Ps[w];

  // Q A-frags (rows q0+16w+nn, k = 32*ks + 8*quad + j)
  const ushort* Qrow = Q + ((size_t)(b * HQ + h) * NN + q0 + w * 16 + nn) * DD;
  bf16x8 aQ0 = *(const bf16x8*)(Qrow + quad * 8);
  bf16x8 aQ1 = *(const bf16x8*)(Qrow + 32 + quad * 8);

  const ushort* Kb  = K  + (size_t)(b * HKV + kvh) * NN * DD;
  const ushort* Vtb = Vt + (size_t)(b * HKV + kvh) * DD * NN;

  f32x4 acc[4];                       // [dt]: O rows quad*4+r, cols dt*16+nn
#pragma unroll
  for (int i = 0; i < 4; i++) acc[i] = (f32x4){0.f, 0.f, 0.f, 0.f};
  float mstate[4], lstate[4];
#pragma unroll
  for (int r = 0; r < 4; r++) { mstate[r] = -1e30f; lstate[r] = 0.f; }

  for (int j = 0; j <= qt; j++) {
    __syncthreads();                  // prev tile's LDS reads done
    // stage K tile [64 kv][64 d] and V^T tile [64 d][64 kv], 16B chunks
#pragma unroll
    for (int i = 0; i < 2; i++) {
      int c = t + i * 256;
      int r = c >> 3, c8 = c & 7;
      *(uint4*)(&Ks[r * LS + c8 * 8]) = *(const uint4*)(Kb + (size_t)(j * 64 + r) * DD + c8 * 8);
      *(uint4*)(&Vs[r * LS + c8 * 8]) = *(const uint4*)(Vtb + (size_t)r * NN + j * 64 + c8 * 8);
    }
    __syncthreads();

    // S = Q K^T : four 16x16 col-tiles, two k-steps each
    const int ctmax = (j == qt) ? w : 3;
    f32x4 sf[4];
#pragma unroll
    for (int ct = 0; ct < 4; ct++) {
      if (ct > ctmax) break;
      const ushort* kr = &Ks[(ct * 16 + nn) * LS + quad * 8];
      bf16x8 bk0 = *(const bf16x8*)(kr);
      bf16x8 bk1 = *(const bf16x8*)(kr + 32);
      f32x4 c = (f32x4){0.f, 0.f, 0.f, 0.f};
      c = __builtin_amdgcn_mfma_f32_16x16x32_bf16(aQ0, bk0, c, 0, 0, 0);
      c = __builtin_amdgcn_mfma_f32_16x16x32_bf16(aQ1, bk1, c, 0, 0, 0);
      sf[ct] = c;
    }

    // scale + causal mask; s[ct][r] = S[row=quad*4+r][col=ct*16+nn]
    float s[4][4];
#pragma unroll
    for (int ct = 0; ct < 4; ct++) {
#pragma unroll
      for (int r = 0; r < 4; r++) {
        float v = -1e30f;
        if (ct <= ctmax) {
          v = sf[ct][r] * 0.125f;
          if (j == qt && (ct * 16 + nn) > (w * 16 + quad * 4 + r)) v = -1e30f;
        }
        s[ct][r] = v;
      }
    }
    // row max over 4 ct + 16 lanes of the quad
    float mt[4];
#pragma unroll
    for (int r = 0; r < 4; r++)
      mt[r] = fmaxf(fmaxf(s[0][r], s[1][r]), fmaxf(s[2][r], s[3][r]));
#pragma unroll
    for (int off = 1; off < 16; off <<= 1)
#pragma unroll
      for (int r = 0; r < 4; r++) mt[r] = fmaxf(mt[r], __shfl_xor(mt[r], off));

    float alpha[4];
#pragma unroll
    for (int r = 0; r < 4; r++) {
      float mn = fmaxf(mstate[r], mt[r]);
      alpha[r] = __expf(mstate[r] - mn);
      mstate[r] = mn;
    }
    float lsum[4] = {0.f, 0.f, 0.f, 0.f};
#pragma unroll
    for (int ct = 0; ct < 4; ct++)
#pragma unroll
      for (int r = 0; r < 4; r++) {
        float p = __expf(s[ct][r] - mstate[r]);
        s[ct][r] = p;
        lsum[r] += p;
      }
#pragma unroll
    for (int off = 1; off < 16; off <<= 1)
#pragma unroll
      for (int r = 0; r < 4; r++) lsum[r] += __shfl_xor(lsum[r], off);
#pragma unroll
    for (int r = 0; r < 4; r++) lstate[r] = lstate[r] * alpha[r] + lsum[r];
#pragma unroll
    for (int dt = 0; dt < 4; dt++)
#pragma unroll
      for (int r = 0; r < 4; r++) acc[dt][r] *= alpha[r];

    // P (C-layout) -> wave-private LDS (bf16); masked cols store 0
#pragma unroll
    for (int ct = 0; ct < 4; ct++)
#pragma unroll
      for (int r = 0; r < 4; r++)
        PsW[(quad * 4 + r) * LS + ct * 16 + nn] = f2bs(s[ct][r]);

    // PV: A = P (A-layout re-read), B = V (from V^T tile)
    bf16x8 aP0 = *(const bf16x8*)(&PsW[nn * LS + quad * 8]);
    bf16x8 aP1 = *(const bf16x8*)(&PsW[nn * LS + 32 + quad * 8]);
#pragma unroll
    for (int dt = 0; dt < 4; dt++) {
      const ushort* vr = &Vs[(dt * 16 + nn) * LS + quad * 8];
      bf16x8 bv0 = *(const bf16x8*)(vr);
      bf16x8 bv1 = *(const bf16x8*)(vr + 32);
      acc[dt] = __builtin_amdgcn_mfma_f32_16x16x32_bf16(aP0, bv0, acc[dt], 0, 0, 0);
      acc[dt] = __builtin_amdgcn_mfma_f32_16x16x32_bf16(aP1, bv1, acc[dt], 0, 0, 0);
    }
  }

  float linv[4];
#pragma unroll
  for (int r = 0; r < 4; r++) linv[r] = 1.f / (lstate[r] + 1e-8f);
#pragma unroll
  for (int dt = 0; dt < 4; dt++)
#pragma unroll
    for (int r = 0; r < 4; r++)
      O[(size_t)(b * NN + q0 + w * 16 + quad * 4 + r) * HID + h * DD + dt * 16 + nn] =
          acc[dt][r] * linv[r];
}

// ---------------------------------------------------------------------------
extern "C" void kernel_launch(void* const* d_in, const int* in_sizes, int n_in,
                              void* d_out, int out_size, void* d_ws, size_t ws_size,
                              hipStream_t stream)
{
  const float* hid = (const float*)d_in[0];
  const int*   pos = (const int*)  d_in[1];
  const float* qw  = (const float*)d_in[2];
  const float* qb  = (const float*)d_in[3];
  const float* kw  = (const float*)d_in[4];
  const float* kb  = (const float*)d_in[5];
  const float* vw  = (const float*)d_in[6];
  const float* vb  = (const float*)d_in[7];
  const float* ow  = (const float*)d_in[8];
  float* outp = (float*)d_out;

  // ws: qkv fp32 [4096*1152] | Q bf16 | K bf16 | Vt bf16 ; O fp32 reuses qkv
  float*  qkv = (float*)d_ws;
  ushort* Qb  = (ushort*)(qkv + (size_t)4096 * QKV_COLS);
  ushort* Kb  = Qb + (size_t)BB * HQ  * NN * DD;
  ushort* Vtb = Kb + (size_t)BB * HKV * NN * DD;
  float*  Ob  = qkv;

  gemm_kernel<<<dim3(14, 64), 256, 0, stream>>>(hid, qw, qb, qkv,        896, QKV_COLS);
  gemm_kernel<<<dim3(2, 64),  256, 0, stream>>>(hid, kw, kb, qkv + 896,  128, QKV_COLS);
  gemm_kernel<<<dim3(2, 64),  256, 0, stream>>>(hid, vw, vb, qkv + 1024, 128, QKV_COLS);
  rope_kernel<<<dim3(4096),   256, 0, stream>>>(qkv, pos, Qb, Kb, Vtb);
  attn_kernel<<<dim3(NN / 64, HQ, BB), 256, 0, stream>>>(Qb, Kb, Vtb, Ob);
  gemm_kernel<<<dim3(14, 64), 256, 0, stream>>>(Ob, ow, nullptr, outp, 896, 896);
}

// Round 3
// 266.714 us; speedup vs baseline: 3.7879x; 1.7606x over previous
//
#include <hip/hip_runtime.h>
#include <math.h>

#define BB 2
#define NN 2048
#define HID 896
#define HQ 14
#define HKV 2
#define DD 64
#define QKV_COLS 1152

typedef __bf16 bf16x8 __attribute__((ext_vector_type(8)));
typedef float f32x4 __attribute__((ext_vector_type(4)));

__device__ inline ushort f2bs(float f) {   // fp32 -> bf16 (RNE), finite inputs
  uint u = __builtin_bit_cast(uint, f);
  u += 0x7FFFu + ((u >> 16) & 1u);
  return (ushort)(u >> 16);
}
__device__ inline float bs2f(ushort u) {
  return __builtin_bit_cast(float, (uint)u << 16);
}

__device__ inline void gload16(const ushort* g, ushort* l) {
  __builtin_amdgcn_global_load_lds(
      (const __attribute__((address_space(1))) uint*)g,
      (__attribute__((address_space(3))) uint*)l, 16, 0, 0);
}

// ---------------------------------------------------------------------------
// fp32 -> bf16 elementwise cast (hidden_states)
// ---------------------------------------------------------------------------
__global__ __launch_bounds__(256)
void cast_bf16_kernel(const float* __restrict__ in, ushort* __restrict__ out)
{
  int i = blockIdx.x * 256 + threadIdx.x;
  float4 v = ((const float4*)in)[i];
  ushort4 o;
  o.x = f2bs(v.x); o.y = f2bs(v.y); o.z = f2bs(v.z); o.w = f2bs(v.w);
  ((ushort4*)out)[i] = o;
}

// ---------------------------------------------------------------------------
// Transpose + cast: in fp32 [K][N] -> out bf16 [N][K] (row stride 896).
// grid (N/32, K/32), 256 threads.
// ---------------------------------------------------------------------------
__global__ __launch_bounds__(256)
void transpose_cast_kernel(const float* __restrict__ in, ushort* __restrict__ out, int N)
{
  __shared__ float tile[32][33];
  const int n0 = blockIdx.x * 32, k0 = blockIdx.y * 32;
  const int tx = threadIdx.x & 31, ty = threadIdx.x >> 5;   // 32 x 8
#pragma unroll
  for (int i = 0; i < 32; i += 8)
    tile[ty + i][tx] = in[(size_t)(k0 + ty + i) * N + n0 + tx];
  __syncthreads();
#pragma unroll
  for (int i = 0; i < 32; i += 8)
    out[(size_t)(n0 + ty + i) * HID + k0 + tx] = f2bs(tile[tx][ty + i]);
}

__global__ __launch_bounds__(256)
void pack_bias_kernel(const float* __restrict__ qb, const float* __restrict__ kb,
                      const float* __restrict__ vb, float* __restrict__ out)
{
  int i = blockIdx.x * 256 + threadIdx.x;
  if (i < QKV_COLS)
    out[i] = (i < 896) ? qb[i] : (i < 1024 ? kb[i - 896] : vb[i - 1024]);
}

// ---------------------------------------------------------------------------
// bf16 MFMA GEMM (m97 structure + XOR bank swizzle):
// out[m][n] = sum_k A[m][k] * Bt[n][k] (+ bias[n]).
// 128x128 tile, BK=32, 256 thr (4 waves, each a 64x64 quadrant, 16 MFMA/step).
// Staging via global_load_lds width 16; LDS chunk c holds global chunk
// c ^ ((row>>1)&3)  -> every frag ds_read_b128 is 2-way bank-aliased (free).
// ---------------------------------------------------------------------------
template <bool OUT_BF16>
__global__ __launch_bounds__(256)
void gemm_mfma(const ushort* __restrict__ A, const ushort* __restrict__ Bt,
               const float* __restrict__ bias, void* __restrict__ out,
               int K, int ldout)
{
  const int n0 = blockIdx.x * 128;
  const int m0 = blockIdx.y * 128;
  __shared__ ushort As[128 * 32];
  __shared__ ushort Bs[128 * 32];
  const int t = threadIdx.x;
  const int w = t >> 6, lane = t & 63;
  const int quad = lane >> 4, nn = lane & 15;
  const int wm = (w & 1) * 64, wn = (w >> 1) * 64;

  f32x4 acc[4][4];
#pragma unroll
  for (int i = 0; i < 4; i++)
#pragma unroll
    for (int j = 0; j < 4; j++) acc[i][j] = (f32x4){0.f, 0.f, 0.f, 0.f};

  for (int k0 = 0; k0 < K; k0 += 32) {
    __syncthreads();
    // stage A[128x32] and Bt[128x32]; 8 chunks of 1024B each, 2 per wave
#pragma unroll
    for (int c = 0; c < 2; c++) {
      int ch = w * 2 + c;
      int r  = ch * 16 + (lane >> 2);
      int cl = lane & 3;
      int cg = cl ^ ((r >> 1) & 3);
      gload16(A  + (size_t)(m0 + r) * K + k0 + cg * 8, &As[r * 32 + cl * 8]);
      gload16(Bt + (size_t)(n0 + r) * K + k0 + cg * 8, &Bs[r * 32 + cl * 8]);
    }
    __syncthreads();

    bf16x8 aF[4], bF[4];
#pragma unroll
    for (int i = 0; i < 4; i++) {
      int ra = wm + i * 16 + nn;
      aF[i] = *(const bf16x8*)(&As[ra * 32 + (quad ^ ((ra >> 1) & 3)) * 8]);
      int rb = wn + i * 16 + nn;
      bF[i] = *(const bf16x8*)(&Bs[rb * 32 + (quad ^ ((rb >> 1) & 3)) * 8]);
    }
#pragma unroll
    for (int i = 0; i < 4; i++)
#pragma unroll
      for (int j = 0; j < 4; j++)
        acc[i][j] = __builtin_amdgcn_mfma_f32_16x16x32_bf16(aF[i], bF[j], acc[i][j], 0, 0, 0);
  }

#pragma unroll
  for (int j = 0; j < 4; j++) {
    const int col = n0 + wn + j * 16 + nn;
    const float bv = bias ? bias[col] : 0.f;
#pragma unroll
    for (int i = 0; i < 4; i++) {
      const int row = m0 + wm + i * 16 + quad * 4;
#pragma unroll
      for (int r = 0; r < 4; r++) {
        float v = acc[i][j][r] + bv;
        if (OUT_BF16)
          ((ushort*)out)[(size_t)(row + r) * ldout + col] = f2bs(v);
        else
          ((float*)out)[(size_t)(row + r) * ldout + col] = v;
      }
    }
  }
}

// ---------------------------------------------------------------------------
// RoPE + scatter (bf16 in): qkv [4096 x 1152] bf16 ->
// Q [B,HQ,N,D], K [B,HKV,N,D], Vt [B,HKV,D,N] all bf16
// ---------------------------------------------------------------------------
__global__ __launch_bounds__(256)
void rope_kernel(const ushort* __restrict__ qkv, const int* __restrict__ pos_ids,
                 ushort* __restrict__ Qo, ushort* __restrict__ Ko, ushort* __restrict__ Vto)
{
  const int m = blockIdx.x;
  const int b = m >> 11, n = m & (NN - 1);
  const int t = threadIdx.x;
  __shared__ float cs[32], sn[32];
  if (t < 32) {
    float inv = exp2f(-(float)t * (19.9315685693241741f / 32.0f));
    float f = (float)pos_ids[m] * inv;
    float sv, cv;
    sincosf(f, &sv, &cv);
    cs[t] = cv; sn[t] = sv;
  }
  __syncthreads();
  const ushort* row = qkv + (size_t)m * QKV_COLS;
#pragma unroll
  for (int it = 0; it < 2; it++) {
    int idx = t + it * 256;
    int hh = idx >> 5, d = idx & 31;
    const ushort* src; ushort* dst;
    if (hh < HQ) {
      src = row + hh * DD;
      dst = Qo + ((size_t)(b * HQ + hh) * NN + n) * DD;
    } else {
      int kh = hh - HQ;
      src = row + HID + kh * DD;
      dst = Ko + ((size_t)(b * HKV + kh) * NN + n) * DD;
    }
    float x1 = bs2f(src[d]), x2 = bs2f(src[d + 32]);
    dst[d]      = f2bs(x1 * cs[d] - x2 * sn[d]);
    dst[d + 32] = f2bs(x2 * cs[d] + x1 * sn[d]);
  }
  if (t < 128) {
    int hh = t >> 6, d = t & 63;
    Vto[((size_t)(b * HKV + hh) * DD + d) * NN + n] = row[HID + HKV * DD + hh * DD + d];
  }
}

// ---------------------------------------------------------------------------
// bf16 MFMA flash attention (as round 2), O stored as bf16.
// ---------------------------------------------------------------------------
#define LS 72
__global__ __launch_bounds__(256)
void attn_kernel(const ushort* __restrict__ Q, const ushort* __restrict__ K,
                 const ushort* __restrict__ Vt, ushort* __restrict__ O)
{
  const int qt = (int)gridDim.x - 1 - (int)blockIdx.x;  // long blocks first
  const int h = blockIdx.y, b = blockIdx.z;
  const int kvh = h / (HQ / HKV);
  const int q0 = qt * 64;

  __shared__ ushort Ks[64 * LS];
  __shared__ ushort Vs[64 * LS];     // V^T tile: [d][kv]
  __shared__ ushort Ps[4][16 * LS];  // wave-private P

  const int t = threadIdx.x;
  const int w = t >> 6, lane = t & 63;
  const int quad = lane >> 4, nn = lane & 15;
  ushort* PsW = Ps[w];

  const ushort* Qrow = Q + ((size_t)(b * HQ + h) * NN + q0 + w * 16 + nn) * DD;
  bf16x8 aQ0 = *(const bf16x8*)(Qrow + quad * 8);
  bf16x8 aQ1 = *(const bf16x8*)(Qrow + 32 + quad * 8);

  const ushort* Kb  = K  + (size_t)(b * HKV + kvh) * NN * DD;
  const ushort* Vtb = Vt + (size_t)(b * HKV + kvh) * DD * NN;

  f32x4 acc[4];
#pragma unroll
  for (int i = 0; i < 4; i++) acc[i] = (f32x4){0.f, 0.f, 0.f, 0.f};
  float mstate[4], lstate[4];
#pragma unroll
  for (int r = 0; r < 4; r++) { mstate[r] = -1e30f; lstate[r] = 0.f; }

  for (int j = 0; j <= qt; j++) {
    __syncthreads();
#pragma unroll
    for (int i = 0; i < 2; i++) {
      int c = t + i * 256;
      int r = c >> 3, c8 = c & 7;
      *(uint4*)(&Ks[r * LS + c8 * 8]) = *(const uint4*)(Kb + (size_t)(j * 64 + r) * DD + c8 * 8);
      *(uint4*)(&Vs[r * LS + c8 * 8]) = *(const uint4*)(Vtb + (size_t)r * NN + j * 64 + c8 * 8);
    }
    __syncthreads();

    const int ctmax = (j == qt) ? w : 3;
    f32x4 sf[4];
#pragma unroll
    for (int ct = 0; ct < 4; ct++) {
      if (ct > ctmax) break;
      const ushort* kr = &Ks[(ct * 16 + nn) * LS + quad * 8];
      bf16x8 bk0 = *(const bf16x8*)(kr);
      bf16x8 bk1 = *(const bf16x8*)(kr + 32);
      f32x4 c = (f32x4){0.f, 0.f, 0.f, 0.f};
      c = __builtin_amdgcn_mfma_f32_16x16x32_bf16(aQ0, bk0, c, 0, 0, 0);
      c = __builtin_amdgcn_mfma_f32_16x16x32_bf16(aQ1, bk1, c, 0, 0, 0);
      sf[ct] = c;
    }

    float s[4][4];
#pragma unroll
    for (int ct = 0; ct < 4; ct++) {
#pragma unroll
      for (int r = 0; r < 4; r++) {
        float v = -1e30f;
        if (ct <= ctmax) {
          v = sf[ct][r] * 0.125f;
          if (j == qt && (ct * 16 + nn) > (w * 16 + quad * 4 + r)) v = -1e30f;
        }
        s[ct][r] = v;
      }
    }
    float mt[4];
#pragma unroll
    for (int r = 0; r < 4; r++)
      mt[r] = fmaxf(fmaxf(s[0][r], s[1][r]), fmaxf(s[2][r], s[3][r]));
#pragma unroll
    for (int off = 1; off < 16; off <<= 1)
#pragma unroll
      for (int r = 0; r < 4; r++) mt[r] = fmaxf(mt[r], __shfl_xor(mt[r], off));

    float alpha[4];
#pragma unroll
    for (int r = 0; r < 4; r++) {
      float mn = fmaxf(mstate[r], mt[r]);
      alpha[r] = __expf(mstate[r] - mn);
      mstate[r] = mn;
    }
    float lsum[4] = {0.f, 0.f, 0.f, 0.f};
#pragma unroll
    for (int ct = 0; ct < 4; ct++)
#pragma unroll
      for (int r = 0; r < 4; r++) {
        float p = __expf(s[ct][r] - mstate[r]);
        s[ct][r] = p;
        lsum[r] += p;
      }
#pragma unroll
    for (int off = 1; off < 16; off <<= 1)
#pragma unroll
      for (int r = 0; r < 4; r++) lsum[r] += __shfl_xor(lsum[r], off);
#pragma unroll
    for (int r = 0; r < 4; r++) lstate[r] = lstate[r] * alpha[r] + lsum[r];
#pragma unroll
    for (int dt = 0; dt < 4; dt++)
#pragma unroll
      for (int r = 0; r < 4; r++) acc[dt][r] *= alpha[r];

#pragma unroll
    for (int ct = 0; ct < 4; ct++)
#pragma unroll
      for (int r = 0; r < 4; r++)
        PsW[(quad * 4 + r) * LS + ct * 16 + nn] = f2bs(s[ct][r]);

    bf16x8 aP0 = *(const bf16x8*)(&PsW[nn * LS + quad * 8]);
    bf16x8 aP1 = *(const bf16x8*)(&PsW[nn * LS + 32 + quad * 8]);
#pragma unroll
    for (int dt = 0; dt < 4; dt++) {
      const ushort* vr = &Vs[(dt * 16 + nn) * LS + quad * 8];
      bf16x8 bv0 = *(const bf16x8*)(vr);
      bf16x8 bv1 = *(const bf16x8*)(vr + 32);
      acc[dt] = __builtin_amdgcn_mfma_f32_16x16x32_bf16(aP0, bv0, acc[dt], 0, 0, 0);
      acc[dt] = __builtin_amdgcn_mfma_f32_16x16x32_bf16(aP1, bv1, acc[dt], 0, 0, 0);
    }
  }

  float linv[4];
#pragma unroll
  for (int r = 0; r < 4; r++) linv[r] = 1.f / (lstate[r] + 1e-8f);
#pragma unroll
  for (int dt = 0; dt < 4; dt++)
#pragma unroll
    for (int r = 0; r < 4; r++)
      O[(size_t)(b * NN + q0 + w * 16 + quad * 4 + r) * HID + h * DD + dt * 16 + nn] =
          f2bs(acc[dt][r] * linv[r]);
}

// ---------------------------------------------------------------------------
extern "C" void kernel_launch(void* const* d_in, const int* in_sizes, int n_in,
                              void* d_out, int out_size, void* d_ws, size_t ws_size,
                              hipStream_t stream)
{
  const float* hid = (const float*)d_in[0];
  const int*   pos = (const int*)  d_in[1];
  const float* qw  = (const float*)d_in[2];
  const float* qb  = (const float*)d_in[3];
  const float* kw  = (const float*)d_in[4];
  const float* kb  = (const float*)d_in[5];
  const float* vw  = (const float*)d_in[6];
  const float* vb  = (const float*)d_in[7];
  const float* ow  = (const float*)d_in[8];
  float* outp = (float*)d_out;

  // ws layout (ushorts): Ah | WqkvT | WoT | qkv | Q | K | Vt | O | bias(fp32)
  ushort* Ah    = (ushort*)d_ws;                          // 4096*896
  ushort* WqkvT = Ah    + (size_t)4096 * HID;             // 1152*896
  ushort* WoT   = WqkvT + (size_t)QKV_COLS * HID;         // 896*896
  ushort* qkv   = WoT   + (size_t)HID * HID;              // 4096*1152
  ushort* Qb    = qkv   + (size_t)4096 * QKV_COLS;        // 2*14*2048*64
  ushort* Kb    = Qb    + (size_t)BB * HQ  * NN * DD;     // 2*2*2048*64
  ushort* Vtb   = Kb    + (size_t)BB * HKV * NN * DD;
  ushort* Ob    = Vtb   + (size_t)BB * HKV * NN * DD;     // 4096*896
  float*  biasQ = (float*)(Ob + (size_t)4096 * HID);      // 1152

  cast_bf16_kernel<<<dim3(4096 * HID / 1024), 256, 0, stream>>>(hid, Ah);
  transpose_cast_kernel<<<dim3(28, 28), 256, 0, stream>>>(qw, WqkvT, 896);
  transpose_cast_kernel<<<dim3(4, 28),  256, 0, stream>>>(kw, WqkvT + (size_t)896 * HID, 128);
  transpose_cast_kernel<<<dim3(4, 28),  256, 0, stream>>>(vw, WqkvT + (size_t)1024 * HID, 128);
  transpose_cast_kernel<<<dim3(28, 28), 256, 0, stream>>>(ow, WoT, 896);
  pack_bias_kernel<<<dim3(5), 256, 0, stream>>>(qb, kb, vb, biasQ);

  gemm_mfma<true><<<dim3(QKV_COLS / 128, 32), 256, 0, stream>>>(Ah, WqkvT, biasQ, qkv, HID, QKV_COLS);
  rope_kernel<<<dim3(4096), 256, 0, stream>>>(qkv, pos, Qb, Kb, Vtb);
  attn_kernel<<<dim3(NN / 64, HQ, BB), 256, 0, stream>>>(Qb, Kb, Vtb, Ob);
  gemm_mfma<false><<<dim3(HID / 128, 32), 256, 0, stream>>>(Ob, WoT, nullptr, outp, HID, HID);
}

// Round 4
// 239.266 us; speedup vs baseline: 4.2225x; 1.1147x over previous
//
#include <hip/hip_runtime.h>
#include <math.h>

#define BB 2
#define NN 2048
#define HID 896
#define HQ 14
#define HKV 2
#define DD 64
#define QKV_COLS 1152

typedef __bf16 bf16x8 __attribute__((ext_vector_type(8)));
typedef float f32x4 __attribute__((ext_vector_type(4)));

__device__ inline ushort f2bs(float f) {   // fp32 -> bf16 (RNE), finite inputs
  uint u = __builtin_bit_cast(uint, f);
  u += 0x7FFFu + ((u >> 16) & 1u);
  return (ushort)(u >> 16);
}
__device__ inline float bs2f(ushort u) {
  return __builtin_bit_cast(float, (uint)u << 16);
}

__device__ inline void gload16(const ushort* g, ushort* l) {
  __builtin_amdgcn_global_load_lds(
      (const __attribute__((address_space(1))) uint*)g,
      (__attribute__((address_space(3))) uint*)l, 16, 0, 0);
}

// ---------------------------------------------------------------------------
// fp32 -> bf16 cast of hidden_states; blocks 0..4 also pack the QKV bias.
// ---------------------------------------------------------------------------
__global__ __launch_bounds__(256)
void cast_bf16_kernel(const float* __restrict__ in, ushort* __restrict__ out,
                      const float* __restrict__ qb, const float* __restrict__ kb,
                      const float* __restrict__ vb, float* __restrict__ biasQ)
{
  int i = blockIdx.x * 256 + threadIdx.x;
  float4 v = ((const float4*)in)[i];
  ushort4 o;
  o.x = f2bs(v.x); o.y = f2bs(v.y); o.z = f2bs(v.z); o.w = f2bs(v.w);
  ((ushort4*)out)[i] = o;
  if (i < QKV_COLS)
    biasQ[i] = (i < 896) ? qb[i] : (i < 1024 ? kb[i - 896] : vb[i - 1024]);
}

// ---------------------------------------------------------------------------
// Fused transpose+cast of q/k/v weights: fp32 [K][Nsrc] -> bf16 WqkvT [1152][896]
// grid (36, 28): x<28 -> qw, 28..31 -> kw, 32..35 -> vw.
// ---------------------------------------------------------------------------
__global__ __launch_bounds__(256)
void qkvw_pack_kernel(const float* __restrict__ qw, const float* __restrict__ kw,
                      const float* __restrict__ vw, ushort* __restrict__ out)
{
  __shared__ float tile[32][33];
  const int bx = blockIdx.x, k0 = blockIdx.y * 32;
  const float* src; int N, n0, drow;
  if (bx < 28)      { src = qw; N = 896; n0 = bx * 32;        drow = n0; }
  else if (bx < 32) { src = kw; N = 128; n0 = (bx - 28) * 32; drow = 896 + n0; }
  else              { src = vw; N = 128; n0 = (bx - 32) * 32; drow = 1024 + n0; }
  const int tx = threadIdx.x & 31, ty = threadIdx.x >> 5;
#pragma unroll
  for (int i = 0; i < 32; i += 8)
    tile[ty + i][tx] = src[(size_t)(k0 + ty + i) * N + n0 + tx];
  __syncthreads();
#pragma unroll
  for (int i = 0; i < 32; i += 8)
    out[(size_t)(drow + ty + i) * HID + k0 + tx] = f2bs(tile[tx][ty + i]);
}

__global__ __launch_bounds__(256)
void transpose_cast_kernel(const float* __restrict__ in, ushort* __restrict__ out, int N)
{
  __shared__ float tile[32][33];
  const int n0 = blockIdx.x * 32, k0 = blockIdx.y * 32;
  const int tx = threadIdx.x & 31, ty = threadIdx.x >> 5;
#pragma unroll
  for (int i = 0; i < 32; i += 8)
    tile[ty + i][tx] = in[(size_t)(k0 + ty + i) * N + n0 + tx];
  __syncthreads();
#pragma unroll
  for (int i = 0; i < 32; i += 8)
    out[(size_t)(n0 + ty + i) * HID + k0 + tx] = f2bs(tile[tx][ty + i]);
}

// ---------------------------------------------------------------------------
// bf16 MFMA GEMM, 64x128 tile (M x N), BK=32, 256 thr / 4 waves (wave = 32x64).
// out = A[m][k] * Bt[n][k] (+bias). global_load_lds staging + XOR bank swizzle.
// ---------------------------------------------------------------------------
template <bool OUT_BF16>
__global__ __launch_bounds__(256)
void gemm_mfma(const ushort* __restrict__ A, const ushort* __restrict__ Bt,
               const float* __restrict__ bias, void* __restrict__ out,
               int K, int ldout)
{
  const int n0 = blockIdx.x * 128;
  const int m0 = blockIdx.y * 64;
  __shared__ ushort As[64 * 32];
  __shared__ ushort Bs[128 * 32];
  const int t = threadIdx.x;
  const int w = t >> 6, lane = t & 63;
  const int quad = lane >> 4, nn = lane & 15;
  const int wm = (w & 1) * 32, wn = (w >> 1) * 64;

  f32x4 acc[2][4];
#pragma unroll
  for (int i = 0; i < 2; i++)
#pragma unroll
    for (int j = 0; j < 4; j++) acc[i][j] = (f32x4){0.f, 0.f, 0.f, 0.f};

  for (int k0 = 0; k0 < K; k0 += 32) {
    __syncthreads();
    // 12 chunks of 1024B (A: 4, B: 8), 3 per wave
#pragma unroll
    for (int c = 0; c < 3; c++) {
      int ch = w * 3 + c;
      int rr = (lane >> 2), cl = lane & 3;
      if (ch < 4) {
        int r = ch * 16 + rr;
        int cg = cl ^ ((r >> 1) & 3);
        gload16(A + (size_t)(m0 + r) * K + k0 + cg * 8, &As[r * 32 + cl * 8]);
      } else {
        int r = (ch - 4) * 16 + rr;
        int cg = cl ^ ((r >> 1) & 3);
        gload16(Bt + (size_t)(n0 + r) * K + k0 + cg * 8, &Bs[r * 32 + cl * 8]);
      }
    }
    __syncthreads();

    bf16x8 aF[2], bF[4];
#pragma unroll
    for (int i = 0; i < 2; i++) {
      int ra = wm + i * 16 + nn;
      aF[i] = *(const bf16x8*)(&As[ra * 32 + (quad ^ ((ra >> 1) & 3)) * 8]);
    }
#pragma unroll
    for (int j = 0; j < 4; j++) {
      int rb = wn + j * 16 + nn;
      bF[j] = *(const bf16x8*)(&Bs[rb * 32 + (quad ^ ((rb >> 1) & 3)) * 8]);
    }
#pragma unroll
    for (int i = 0; i < 2; i++)
#pragma unroll
      for (int j = 0; j < 4; j++)
        acc[i][j] = __builtin_amdgcn_mfma_f32_16x16x32_bf16(aF[i], bF[j], acc[i][j], 0, 0, 0);
  }

#pragma unroll
  for (int j = 0; j < 4; j++) {
    const int col = n0 + wn + j * 16 + nn;
    const float bv = bias ? bias[col] : 0.f;
#pragma unroll
    for (int i = 0; i < 2; i++) {
      const int row = m0 + wm + i * 16 + quad * 4;
#pragma unroll
      for (int r = 0; r < 4; r++) {
        float v = acc[i][j][r] + bv;
        if (OUT_BF16)
          ((ushort*)out)[(size_t)(row + r) * ldout + col] = f2bs(v);
        else
          ((float*)out)[(size_t)(row + r) * ldout + col] = v;
      }
    }
  }
}

// ---------------------------------------------------------------------------
// RoPE + scatter (bf16): qkv [4096x1152] -> Q [B,HQ,N,D], K [B,HKV,N,D],
// Vt [B,HKV,D,N]
// ---------------------------------------------------------------------------
__global__ __launch_bounds__(256)
void rope_kernel(const ushort* __restrict__ qkv, const int* __restrict__ pos_ids,
                 ushort* __restrict__ Qo, ushort* __restrict__ Ko, ushort* __restrict__ Vto)
{
  const int m = blockIdx.x;
  const int b = m >> 11, n = m & (NN - 1);
  const int t = threadIdx.x;
  __shared__ float cs[32], sn[32];
  if (t < 32) {
    float inv = exp2f(-(float)t * (19.9315685693241741f / 32.0f));
    float f = (float)pos_ids[m] * inv;
    float sv, cv;
    sincosf(f, &sv, &cv);
    cs[t] = cv; sn[t] = sv;
  }
  __syncthreads();
  const ushort* row = qkv + (size_t)m * QKV_COLS;
#pragma unroll
  for (int it = 0; it < 2; it++) {
    int idx = t + it * 256;
    int hh = idx >> 5, d = idx & 31;
    const ushort* src; ushort* dst;
    if (hh < HQ) {
      src = row + hh * DD;
      dst = Qo + ((size_t)(b * HQ + hh) * NN + n) * DD;
    } else {
      int kh = hh - HQ;
      src = row + HID + kh * DD;
      dst = Ko + ((size_t)(b * HKV + kh) * NN + n) * DD;
    }
    float x1 = bs2f(src[d]), x2 = bs2f(src[d + 32]);
    dst[d]      = f2bs(x1 * cs[d] - x2 * sn[d]);
    dst[d + 32] = f2bs(x2 * cs[d] + x1 * sn[d]);
  }
  if (t < 128) {
    int hh = t >> 6, d = t & 63;
    Vto[((size_t)(b * HKV + hh) * DD + d) * NN + n] = row[HID + HKV * DD + hh * DD + d];
  }
}

// ---------------------------------------------------------------------------
// Split-KV bf16 MFMA flash attention, part 1.
// grid.x = 128 (qt*4+c, reversed); qt = Q-tile of 64 rows, c = KV-chunk of 512.
// nc(qt) = qt/8+1 chunks; c >= nc exits. qt<8 (nc==1) writes final O directly;
// otherwise writes unnormalized partial (bf16) + m/l (fp32) for the reducer.
// K/V staged via global_load_lds w/ XOR swizzle (stride 64, conflict-floor).
// ---------------------------------------------------------------------------
#define LS 72
__global__ __launch_bounds__(256)
void attn_part_kernel(const ushort* __restrict__ Q, const ushort* __restrict__ K,
                      const ushort* __restrict__ Vt, ushort* __restrict__ O,
                      ushort* __restrict__ Opart, float* __restrict__ mpart,
                      float* __restrict__ lpart)
{
  const int qc = (int)gridDim.x - 1 - (int)blockIdx.x;  // heavy blocks first
  const int qt = qc >> 2, c = qc & 3;
  const int nc = (qt >> 3) + 1;
  if (c >= nc) return;
  const int h = blockIdx.y, b = blockIdx.z;
  const int kvh = h / (HQ / HKV);
  const int q0 = qt * 64;
  const int jlo = c * 8, jhi = min(qt, jlo + 7);

  __shared__ ushort Ks[64 * 64];     // [kv][d], chunk-swizzled
  __shared__ ushort Vs[64 * 64];     // [d][kv], chunk-swizzled
  __shared__ ushort Ps[4][16 * LS];  // wave-private P

  const int t = threadIdx.x;
  const int w = t >> 6, lane = t & 63;
  const int quad = lane >> 4, nn = lane & 15;
  ushort* PsW = Ps[w];

  const ushort* Qrow = Q + ((size_t)(b * HQ + h) * NN + q0 + w * 16 + nn) * DD;
  bf16x8 aQ0 = *(const bf16x8*)(Qrow + quad * 8);
  bf16x8 aQ1 = *(const bf16x8*)(Qrow + 32 + quad * 8);

  const ushort* Kb  = K  + (size_t)(b * HKV + kvh) * NN * DD;
  const ushort* Vtb = Vt + (size_t)(b * HKV + kvh) * DD * NN;

  f32x4 acc[4];
#pragma unroll
  for (int i = 0; i < 4; i++) acc[i] = (f32x4){0.f, 0.f, 0.f, 0.f};
  float mstate[4], lstate[4];
#pragma unroll
  for (int r = 0; r < 4; r++) { mstate[r] = -1e30f; lstate[r] = 0.f; }

  const int srow = lane >> 3, scl = lane & 7;   // staging lane decomposition

  for (int j = jlo; j <= jhi; j++) {
    __syncthreads();
    // stage K tile (8 KB) + V^T tile (8 KB): 16 chunk-issues, 4 per wave.
    // LDS image linear in lane order; XOR swizzle applied to global source.
#pragma unroll
    for (int i = 0; i < 2; i++) {
      int r = (w * 2 + i) * 8 + srow;           // 0..63
      int cg = scl ^ (r & 7);
      gload16(Kb + (size_t)(j * 64 + r) * DD + cg * 8, &Ks[r * 64 + scl * 8]);
      gload16(Vtb + (size_t)r * NN + j * 64 + cg * 8, &Vs[r * 64 + scl * 8]);
    }
    __syncthreads();

    const int ctmax = (j == qt) ? w : 3;
    f32x4 sf[4];
#pragma unroll
    for (int ct = 0; ct < 4; ct++) {
      if (ct > ctmax) break;
      int kr = ct * 16 + nn;
      bf16x8 bk0 = *(const bf16x8*)(&Ks[kr * 64 + ((quad ^ (kr & 7)) & 7) * 8]);
      bf16x8 bk1 = *(const bf16x8*)(&Ks[kr * 64 + (((quad + 4) ^ (kr & 7)) & 7) * 8]);
      f32x4 cacc = (f32x4){0.f, 0.f, 0.f, 0.f};
      cacc = __builtin_amdgcn_mfma_f32_16x16x32_bf16(aQ0, bk0, cacc, 0, 0, 0);
      cacc = __builtin_amdgcn_mfma_f32_16x16x32_bf16(aQ1, bk1, cacc, 0, 0, 0);
      sf[ct] = cacc;
    }

    float s[4][4];
#pragma unroll
    for (int ct = 0; ct < 4; ct++) {
#pragma unroll
      for (int r = 0; r < 4; r++) {
        float v = -1e30f;
        if (ct <= ctmax) {
          v = sf[ct][r] * 0.125f;
          if (j == qt && (ct * 16 + nn) > (w * 16 + quad * 4 + r)) v = -1e30f;
        }
        s[ct][r] = v;
      }
    }
    float mt[4];
#pragma unroll
    for (int r = 0; r < 4; r++)
      mt[r] = fmaxf(fmaxf(s[0][r], s[1][r]), fmaxf(s[2][r], s[3][r]));
#pragma unroll
    for (int off = 1; off < 16; off <<= 1)
#pragma unroll
      for (int r = 0; r < 4; r++) mt[r] = fmaxf(mt[r], __shfl_xor(mt[r], off));

    float alpha[4];
#pragma unroll
    for (int r = 0; r < 4; r++) {
      float mn = fmaxf(mstate[r], mt[r]);
      alpha[r] = __expf(mstate[r] - mn);
      mstate[r] = mn;
    }
    float lsum[4] = {0.f, 0.f, 0.f, 0.f};
#pragma unroll
    for (int ct = 0; ct < 4; ct++)
#pragma unroll
      for (int r = 0; r < 4; r++) {
        float p = __expf(s[ct][r] - mstate[r]);
        s[ct][r] = p;
        lsum[r] += p;
      }
#pragma unroll
    for (int off = 1; off < 16; off <<= 1)
#pragma unroll
      for (int r = 0; r < 4; r++) lsum[r] += __shfl_xor(lsum[r], off);
#pragma unroll
    for (int r = 0; r < 4; r++) lstate[r] = lstate[r] * alpha[r] + lsum[r];
#pragma unroll
    for (int dt = 0; dt < 4; dt++)
#pragma unroll
      for (int r = 0; r < 4; r++) acc[dt][r] *= alpha[r];

#pragma unroll
    for (int ct = 0; ct < 4; ct++)
#pragma unroll
      for (int r = 0; r < 4; r++)
        PsW[(quad * 4 + r) * LS + ct * 16 + nn] = f2bs(s[ct][r]);

    bf16x8 aP0 = *(const bf16x8*)(&PsW[nn * LS + quad * 8]);
    bf16x8 aP1 = *(const bf16x8*)(&PsW[nn * LS + 32 + quad * 8]);
#pragma unroll
    for (int dt = 0; dt < 4; dt++) {
      int vr = dt * 16 + nn;
      bf16x8 bv0 = *(const bf16x8*)(&Vs[vr * 64 + ((quad ^ (vr & 7)) & 7) * 8]);
      bf16x8 bv1 = *(const bf16x8*)(&Vs[vr * 64 + (((quad + 4) ^ (vr & 7)) & 7) * 8]);
      acc[dt] = __builtin_amdgcn_mfma_f32_16x16x32_bf16(aP0, bv0, acc[dt], 0, 0, 0);
      acc[dt] = __builtin_amdgcn_mfma_f32_16x16x32_bf16(aP1, bv1, acc[dt], 0, 0, 0);
    }
  }

  const int rowloc = w * 16 + quad * 4;
  if (nc == 1) {
    // single chunk: normalize and write final O
    float linv[4];
#pragma unroll
    for (int r = 0; r < 4; r++) linv[r] = 1.f / (lstate[r] + 1e-8f);
#pragma unroll
    for (int dt = 0; dt < 4; dt++)
#pragma unroll
      for (int r = 0; r < 4; r++)
        O[(size_t)(b * NN + q0 + rowloc + r) * HID + h * DD + dt * 16 + nn] =
            f2bs(acc[dt][r] * linv[r]);
  } else {
    // partial slot index: qt>=8 tiles only, 72 slots per (b,h)
    const int g = qt >> 3;
    const int off = (g == 1) ? (qt - 8) * 2
                  : (g == 2) ? 16 + (qt - 16) * 3
                             : 40 + (qt - 24) * 4;
    const int p = ((b * HQ + h) * 72 + off + c);
    ushort* Op = Opart + (size_t)p * 4096;
#pragma unroll
    for (int dt = 0; dt < 4; dt++)
#pragma unroll
      for (int r = 0; r < 4; r++)
        Op[(rowloc + r) * 64 + dt * 16 + nn] = f2bs(acc[dt][r]);
    if (nn == 0) {
#pragma unroll
      for (int r = 0; r < 4; r++) {
        mpart[(size_t)p * 64 + rowloc + r] = mstate[r];
        lpart[(size_t)p * 64 + rowloc + r] = lstate[r];
      }
    }
  }
}

// ---------------------------------------------------------------------------
// Split-KV reduce: combine nc (2..4) partials per (qt>=8, h, b) Q-tile.
// grid (24, 14, 2), 256 thr: thread = (row = t>>2, 16-col group = t&3).
// ---------------------------------------------------------------------------
__global__ __launch_bounds__(256)
void attn_reduce_kernel(const ushort* __restrict__ Opart, const float* __restrict__ mpart,
                        const float* __restrict__ lpart, ushort* __restrict__ O)
{
  const int qt = 8 + blockIdx.x;
  const int h = blockIdx.y, b = blockIdx.z;
  const int g = qt >> 3;
  const int nc = g + 1;
  const int off = (g == 1) ? (qt - 8) * 2
                : (g == 2) ? 16 + (qt - 16) * 3
                           : 40 + (qt - 24) * 4;
  const int pb = (b * HQ + h) * 72 + off;
  const int t = threadIdx.x;
  const int row = t >> 2, cg = t & 3;

  float mv[4], lv[4];
  float M = -1e30f;
  for (int c = 0; c < nc; c++) {
    mv[c] = mpart[(size_t)(pb + c) * 64 + row];
    lv[c] = lpart[(size_t)(pb + c) * 64 + row];
    M = fmaxf(M, mv[c]);
  }
  float l = 0.f;
  float accv[16];
#pragma unroll
  for (int k = 0; k < 16; k++) accv[k] = 0.f;
  for (int c = 0; c < nc; c++) {
    float wc = __expf(mv[c] - M);
    l += lv[c] * wc;
    const ushort* Op = Opart + (size_t)(pb + c) * 4096 + row * 64 + cg * 16;
#pragma unroll
    for (int k = 0; k < 16; k++) accv[k] += wc * bs2f(Op[k]);
  }
  const float linv = 1.f / (l + 1e-8f);
  ushort ov[16];
#pragma unroll
  for (int k = 0; k < 16; k++) ov[k] = f2bs(accv[k] * linv);
  ushort* Od = O + (size_t)(b * NN + qt * 64 + row) * HID + h * DD + cg * 16;
  *(uint4*)(Od) = *(uint4*)(ov);
  *(uint4*)(Od + 8) = *(uint4*)(ov + 8);
}

// ---------------------------------------------------------------------------
extern "C" void kernel_launch(void* const* d_in, const int* in_sizes, int n_in,
                              void* d_out, int out_size, void* d_ws, size_t ws_size,
                              hipStream_t stream)
{
  const float* hid = (const float*)d_in[0];
  const int*   pos = (const int*)  d_in[1];
  const float* qw  = (const float*)d_in[2];
  const float* qb  = (const float*)d_in[3];
  const float* kw  = (const float*)d_in[4];
  const float* kb  = (const float*)d_in[5];
  const float* vw  = (const float*)d_in[6];
  const float* vb  = (const float*)d_in[7];
  const float* ow  = (const float*)d_in[8];
  float* outp = (float*)d_out;

  // ws (ushort units): WqkvT | WoT | Ah | qkv | Q | K | Vt | Ob | biasQ | m | l
  // Opart (72*28 tiles of 64x64 bf16 = 8.26M elems) overlays [Ah, qkv) (8.39M).
  ushort* WqkvT = (ushort*)d_ws;                          // 1152*896
  ushort* WoT   = WqkvT + (size_t)QKV_COLS * HID;         // 896*896
  ushort* Ah    = WoT   + (size_t)HID * HID;              // 4096*896
  ushort* qkv   = Ah    + (size_t)4096 * HID;             // 4096*1152
  ushort* Qb    = qkv   + (size_t)4096 * QKV_COLS;
  ushort* Kb    = Qb    + (size_t)BB * HQ  * NN * DD;
  ushort* Vtb   = Kb    + (size_t)BB * HKV * NN * DD;
  ushort* Ob    = Vtb   + (size_t)BB * HKV * NN * DD;     // 4096*896
  float*  biasQ = (float*)(Ob + (size_t)4096 * HID);      // 1152
  float*  mpart = biasQ + QKV_COLS;                       // 72*28*64
  float*  lpart = mpart + (size_t)72 * 28 * 64;
  ushort* Opart = Ah;                                     // overlay (dead region)

  cast_bf16_kernel<<<dim3(4096 * HID / 1024), 256, 0, stream>>>(hid, Ah, qb, kb, vb, biasQ);
  qkvw_pack_kernel<<<dim3(36, 28), 256, 0, stream>>>(qw, kw, vw, WqkvT);
  transpose_cast_kernel<<<dim3(28, 28), 256, 0, stream>>>(ow, WoT, 896);

  gemm_mfma<true><<<dim3(QKV_COLS / 128, 64), 256, 0, stream>>>(Ah, WqkvT, biasQ, qkv, HID, QKV_COLS);
  rope_kernel<<<dim3(4096), 256, 0, stream>>>(qkv, pos, Qb, Kb, Vtb);
  attn_part_kernel<<<dim3(128, HQ, BB), 256, 0, stream>>>(Qb, Kb, Vtb, Ob, Opart, mpart, lpart);
  attn_reduce_kernel<<<dim3(24, HQ, BB), 256, 0, stream>>>(Opart, mpart, lpart, Ob);
  gemm_mfma<false><<<dim3(HID / 128, 64), 256, 0, stream>>>(Ob, WoT, nullptr, outp, HID, HID);
}